// Round 3
// 71.369 us; speedup vs baseline: 1.0303x; 1.0303x over previous
//
#include <hip/hip_runtime.h>
#include <math.h>

#define POOL 7
#define NUM_ROIS 300
#define FH 50
#define FW 50
#define FC 512
#define NBINS (POOL * POOL)                    // 49 bins per ROI
#define FMAX_N (FH * FW)                       // 2500 pixels
#define OUT_F4 (NBINS * FC / 4)                // 6272 float4 per ROI

typedef float floatx4 __attribute__((ext_vector_type(4)));  // native vec for nontemporal

// Kernel A: fmax[h][w] = max over C of feature_maps[h][w][c]
// 256-thread blocks, one wave per pixel (4 pixels/block) -> 625 workgroups.
__global__ __launch_bounds__(256) void channel_max_kernel(
    const float* __restrict__ fm, float* __restrict__ fmax_g) {
    int wave = threadIdx.x >> 6;
    int lane = threadIdx.x & 63;
    int pix = blockIdx.x * 4 + wave;            // 0..2499
    const float4* p = (const float4*)(fm + (size_t)pix * FC);
    float4 a = p[lane];
    float4 b = p[lane + 64];
    float m = fmaxf(fmaxf(fmaxf(a.x, a.y), fmaxf(a.z, a.w)),
                    fmaxf(fmaxf(b.x, b.y), fmaxf(b.z, b.w)));
    #pragma unroll
    for (int off = 32; off > 0; off >>= 1)
        m = fmaxf(m, __shfl_down(m, off, 64));
    if (lane == 0) fmax_g[pix] = m;
}

// Kernel B: one block per ROI (300 blocks x 1024 threads).
// Phase 1: stage all 2500 fmax values into LDS (coalesced, once per block).
// Phase 2: lanes 0..48 compute their bin max from LDS.
// Phase 3: all 16 waves stream the 49x512 broadcast slice with nontemporal
//          float4 stores (100 KB/block, 30 MB total = the output floor).
__global__ __launch_bounds__(1024) void pool_write_kernel(
    const float* __restrict__ rois, const float* __restrict__ fmax_g,
    float* __restrict__ out) {
    __shared__ float sf[FMAX_N];
    __shared__ float pooled[NBINS];
    int n = blockIdx.x;                         // roi
    int t = threadIdx.x;

    // Stage fmax -> LDS: 2500 floats, 1024 threads, 3 strided passes.
    for (int idx = t; idx < FMAX_N; idx += 1024)
        sf[idx] = fmax_g[idx];
    __syncthreads();

    if (t < NBINS) {
        int i = t / POOL;                       // row bin
        int j = t - i * POOL;                   // col bin

        // Replicate: r = int32(roi * (1/16)) (truncation; values non-negative).
        int x1 = (int)(rois[n * 5 + 1] * 0.0625f);
        int y1 = (int)(rois[n * 5 + 2] * 0.0625f);
        int x2 = (int)(rois[n * 5 + 3] * 0.0625f);
        int y2 = (int)(rois[n * 5 + 4] * 0.0625f);
        int rh = y2 - y1 + 1;
        int rw = x2 - x1 + 1;

        // Python floor-div on non-negative ints == C int division here.
        int hs = min(max(y1 + (i * rh) / POOL, 0), FH);
        int he = min(max(y1 + ((i + 1) * rh + POOL - 1) / POOL, 0), FH);
        int ws = min(max(x1 + (j * rw) / POOL, 0), FW);
        int we = min(max(x1 + ((j + 1) * rw + POOL - 1) / POOL, 0), FW);

        float m = -INFINITY;                    // empty bin -> -inf (matches ref)
        for (int h = hs; h < he; ++h)
            for (int w = ws; w < we; ++w)
                m = fmaxf(m, sf[h * FW + w]);
        pooled[t] = m;
    }
    __syncthreads();

    // Stream out 49*512 floats = 6272 float4; bin index = f4 >> 7.
    floatx4* o4 = (floatx4*)(out + (size_t)n * NBINS * FC);
    for (int f = t; f < OUT_F4; f += 1024) {
        float m = pooled[f >> 7];
        floatx4 v = {m, m, m, m};
        __builtin_nontemporal_store(v, &o4[f]);
    }
}

extern "C" void kernel_launch(void* const* d_in, const int* in_sizes, int n_in,
                              void* d_out, int out_size, void* d_ws, size_t ws_size,
                              hipStream_t stream) {
    const float* rois = (const float*)d_in[0];          // (300, 5) f32
    const float* feature_maps = (const float*)d_in[1];  // (50, 50, 512) f32
    float* out = (float*)d_out;                         // (300, 7, 7, 512) f32
    float* fmax_g = (float*)d_ws;                       // 2500 floats

    channel_max_kernel<<<FMAX_N / 4, 256, 0, stream>>>(feature_maps, fmax_g);
    pool_write_kernel<<<NUM_ROIS, 1024, 0, stream>>>(rois, fmax_g, out);
}